// Round 11
// baseline (139.577 us; speedup 1.0000x reference)
//
#include <hip/hip_runtime.h>

typedef float f32x4 __attribute__((ext_vector_type(4)));

#define NW_MAX 192    // LDS capacity for per-window arrays (>= 162)
#define CHUNK  1024   // items per sort chunk
#define GCAP   48     // max chunks (ceil(40962/1024) = 41)

// ---------------------------------------------------------------------------
// K1: per-chunk histogram. hist[g*NW + w] = #items in chunk g with window w.
// ---------------------------------------------------------------------------
__global__ __launch_bounds__(1024) void k_hist(
        const int* __restrict__ wid, int N, int NW, int* __restrict__ hist) {
    __shared__ int lh[NW_MAX];
    const int t = threadIdx.x;
    if (t < NW) lh[t] = 0;
    __syncthreads();
    const int i = blockIdx.x * CHUNK + t;
    if (i < N) atomicAdd(&lh[wid[i]], 1);
    __syncthreads();
    if (t < NW) hist[blockIdx.x * NW + t] = lh[t];
}

// ---------------------------------------------------------------------------
// K2: fused scan+rank. Each block redundantly computes the full scan from the
// LDS-staged hist, then its chunk's per-window base, then stable ranks:
// earlier chunk < earlier wave < earlier lane. Emits:
//   order_f[p] = i      (harness output)
//   pos_i[i]   = p - offsets[w]   (slot within window; coalesced in i)
// ---------------------------------------------------------------------------
__global__ __launch_bounds__(1024) void k_order(
        const int* __restrict__ wid, int N, int NW, int G,
        const int* __restrict__ hist,
        int* __restrict__ offsets,
        int* __restrict__ pos_i,
        float* __restrict__ order_f,
        float* __restrict__ counts_f) {
    __shared__ int lh[GCAP * NW_MAX];  // staged hist, stride NW
    __shared__ int lw[CHUNK];          // this chunk's window ids
    __shared__ int cw[16 * NW_MAX];    // per-wave window counts, stride NW
    __shared__ int cnt_s[NW_MAX];
    __shared__ int lbase[NW_MAX];
    __shared__ int loff[NW_MAX];
    __shared__ int sc[256];

    const int t = threadIdx.x;
    const int g = blockIdx.x;
    const int total = G * NW;

    for (int idx = t; idx < total; idx += 1024) lh[idx] = hist[idx];
    for (int idx = t; idx < 16 * NW; idx += 1024) cw[idx] = 0;

    const int i = g * CHUNK + t;
    const int w = (i < N) ? wid[i] : -1;
    lw[t] = w;
    const int wv = t >> 6;             // wave index 0..15
    __syncthreads();

    if (w >= 0) atomicAdd(&cw[wv * NW + w], 1);

    if (t < NW) {                      // counts per window (from staged hist)
        int s = 0;
        for (int gg = 0; gg < G; ++gg) s += lh[gg * NW + t];
        cnt_s[t] = s;
    }
    __syncthreads();                   // cw atomics + cnt_s ready

    // exclusive scan over windows (Hillis-Steele on 256 lanes)
    if (t < 256) sc[t] = (t < NW) ? cnt_s[t] : 0;
    __syncthreads();
    for (int d = 1; d < 256; d <<= 1) {
        int v = 0;
        if (t < 256 && t >= d) v = sc[t - d];
        __syncthreads();
        if (t < 256) sc[t] += v;
        __syncthreads();
    }

    if (t < NW) {
        const int offw = (t == 0) ? 0 : sc[t - 1];
        loff[t] = offw;
        int b = offw;                  // base for this chunk, window t
        for (int gg = 0; gg < g; ++gg) b += lh[gg * NW + t];
        lbase[t] = b;
        if (g == 0) {
            offsets[t] = offw;
            counts_f[t] = (float)cnt_s[t];
            if (t == 0) offsets[NW] = sc[NW - 1];
        }
    }
    __syncthreads();

    if (i < N) {
        int cr = 0;                    // items of w in earlier waves
        #pragma unroll
        for (int wv2 = 0; wv2 < 16; ++wv2)
            if (wv2 < wv) cr += cw[wv2 * NW + w];
        const int lane = t & 63;
        const int wb = t & ~63;
        int r = 0;                     // stable rank within wave
        #pragma unroll
        for (int j = 0; j < 63; ++j)
            if (j < lane && lw[wb + j] == w) ++r;   // broadcast LDS reads
        const int p = lbase[w] + cr + r;            // global sorted position
        order_f[p] = (float)i;
        pos_i[i] = p - loff[w];                     // slot within window
    }
}

// ---------------------------------------------------------------------------
// K3: batch-tiled scatter (data role) + pad zero-fill (pad role).
//  - blockIdx.y = batch; x-major dispatch order keeps the ACTIVE WRITE SET
//    to ~1-2 batches (27-53 MB) => MALL buffers the random 512B writes and
//    evicts to HBM in near-address order.
//  - data role: block reads 32 consecutive x rows (16 KB contiguous), writes
//    each row to its (w, slot) in out[b] — random but MALL-resident.
//  - pad role: grid-stride zero-fill of pad slots for this batch only.
//  - regular (allocating) loads & stores: we WANT MALL to hold the writes.
// ---------------------------------------------------------------------------
__global__ __launch_bounds__(256) void k_scatter(
        const f32x4* __restrict__ x,
        const int* __restrict__ wid,
        const int* __restrict__ pos_i,
        const int* __restrict__ offsets,
        int N, int NW, int MWS, int DB, int S16,
        f32x4* __restrict__ out) {
    const int b = blockIdx.y;
    const int t = threadIdx.x;
    const long long ob = (long long)b * NW * MWS;

    if ((int)blockIdx.x < DB) {
        // ---- data role: 32 consecutive source rows ----
        const int rl = t >> 5;                    // row-engine 0..7
        const int c4 = t & 31;                    // f32x4 lane in row
        const int i0 = blockIdx.x * 32;
        const long long xb = (long long)b * N;

        int wk[4], sk[4];
        #pragma unroll
        for (int k = 0; k < 4; ++k) {
            const int i = i0 + k * 8 + rl;
            wk[k] = (i < N) ? wid[i] : -1;        // uniform per row-engine
            sk[k] = (i < N) ? pos_i[i] : 0;
        }
        f32x4 v[4];
        #pragma unroll
        for (int k = 0; k < 4; ++k) {
            const int i = i0 + k * 8 + rl;
            const int ic = (i < N) ? i : 0;       // clamped addr
            v[k] = x[(xb + ic) * 32 + c4];        // sequential 512B rows
        }
        #pragma unroll
        for (int k = 0; k < 4; ++k) {
            if (wk[k] >= 0)
                out[(ob + (long long)wk[k] * MWS + sk[k]) * 32 + c4] = v[k];
        }
    } else {
        // ---- pad role: zero-fill slots s >= cnt[w] for this batch ----
        const int e  = t >> 5;                    // slot-engine 0..7
        const int c4 = t & 31;
        const int ntup = NW * S16;
        const int stride = gridDim.x - DB;
        const f32x4 z = {0.f, 0.f, 0.f, 0.f};
        for (int tup = blockIdx.x - DB; tup < ntup; tup += stride) {
            const int w  = tup / S16;
            const int s0 = (tup - w * S16) * 16;
            const int cnt = offsets[w + 1] - offsets[w];
            if (s0 + 16 <= cnt) continue;         // fully data: skip
            const long long rb = ob + (long long)w * MWS;
            #pragma unroll
            for (int r = 0; r < 2; ++r) {
                const int s = s0 + e * 2 + r;
                if (s >= MWS || s < cnt) continue;
                out[(rb + s) * 32 + c4] = z;
            }
        }
    }
}

// ---------------------------------------------------------------------------
extern "C" void kernel_launch(void* const* d_in, const int* in_sizes, int n_in,
                              void* d_out, int out_size, void* d_ws, size_t ws_size,
                              hipStream_t stream) {
    const float* x   = (const float*)d_in[0];
    const int*   wid = (const int*)d_in[1];

    const int N  = in_sizes[1];                 // 40962
    const int C  = 128;                         // per reference
    const int NW = 162;                         // per reference
    const int B  = (int)((long long)in_sizes[0] / ((long long)N * C));

    const long long win_elems = (long long)out_size - N - NW;
    const int MWS = (int)(win_elems / ((long long)B * NW * C));

    const int G = (N + CHUNK - 1) / CHUNK;      // 41 chunks

    // ws layout (ints): hist[G*NW] | offsets[NW+1] | pos_i[N]
    int* hist    = (int*)d_ws;
    int* offsets = hist + (size_t)G * NW;
    int* pos_i   = offsets + (NW + 1);

    float* out_f    = (float*)d_out;
    float* order_f  = out_f + win_elems;
    float* counts_f = order_f + N;

    const int DB   = (N + 31) / 32;             // data blocks per batch (1281)
    const int PADB = 256;                       // pad blocks per batch
    const int S16  = (MWS + 15) / 16;

    k_hist   <<<G, CHUNK, 0, stream>>>(wid, N, NW, hist);
    k_order  <<<G, CHUNK, 0, stream>>>(wid, N, NW, G, hist, offsets,
                                       pos_i, order_f, counts_f);
    k_scatter<<<dim3(DB + PADB, B), 256, 0, stream>>>((const f32x4*)x, wid,
                                                      pos_i, offsets,
                                                      N, NW, MWS, DB, S16,
                                                      (f32x4*)out_f);
}

// Round 12
// 103.860 us; speedup vs baseline: 1.3439x; 1.3439x over previous
//
#include <hip/hip_runtime.h>

typedef float f32x4 __attribute__((ext_vector_type(4)));

#define NW_MAX 192    // LDS capacity for per-window arrays (>= 162)
#define CHUNK  1024   // items per sort chunk
#define GCAP   48     // max chunks (ceil(40962/1024) = 41)
#define RPB    64     // output rows per gather block (8 consecutive per engine)

// ---------------------------------------------------------------------------
// K1: per-chunk histogram. hist[g*NW + w] = #items in chunk g with window w.
// ---------------------------------------------------------------------------
__global__ __launch_bounds__(1024) void k_hist(
        const int* __restrict__ wid, int N, int NW, int* __restrict__ hist) {
    __shared__ int lh[NW_MAX];
    const int t = threadIdx.x;
    if (t < NW) lh[t] = 0;
    __syncthreads();
    const int i = blockIdx.x * CHUNK + t;
    if (i < N) atomicAdd(&lh[wid[i]], 1);
    __syncthreads();
    if (t < NW) hist[blockIdx.x * NW + t] = lh[t];
}

// ---------------------------------------------------------------------------
// K2: fused scan+rank (frozen since R7). Each block redundantly computes the
// full scan from the LDS-staged hist, then its chunk's per-window base, then
// stable ranks: earlier chunk < earlier wave < earlier lane.
// ---------------------------------------------------------------------------
__global__ __launch_bounds__(1024) void k_order(
        const int* __restrict__ wid, int N, int NW, int G,
        const int* __restrict__ hist,
        int* __restrict__ offsets,
        int* __restrict__ sorted_src,
        float* __restrict__ order_f,
        float* __restrict__ counts_f) {
    __shared__ int lh[GCAP * NW_MAX];  // staged hist, stride NW
    __shared__ int lw[CHUNK];          // this chunk's window ids
    __shared__ int cw[16 * NW_MAX];    // per-wave window counts, stride NW
    __shared__ int cnt_s[NW_MAX];
    __shared__ int lbase[NW_MAX];
    __shared__ int sc[256];

    const int t = threadIdx.x;
    const int g = blockIdx.x;
    const int total = G * NW;

    for (int idx = t; idx < total; idx += 1024) lh[idx] = hist[idx];
    for (int idx = t; idx < 16 * NW; idx += 1024) cw[idx] = 0;

    const int i = g * CHUNK + t;
    const int w = (i < N) ? wid[i] : -1;
    lw[t] = w;
    const int wv = t >> 6;             // wave index 0..15
    __syncthreads();

    if (w >= 0) atomicAdd(&cw[wv * NW + w], 1);

    if (t < NW) {                      // counts per window (from staged hist)
        int s = 0;
        for (int gg = 0; gg < G; ++gg) s += lh[gg * NW + t];
        cnt_s[t] = s;
    }
    __syncthreads();                   // cw atomics + cnt_s ready

    // exclusive scan over windows (Hillis-Steele on 256 lanes)
    if (t < 256) sc[t] = (t < NW) ? cnt_s[t] : 0;
    __syncthreads();
    for (int d = 1; d < 256; d <<= 1) {
        int v = 0;
        if (t < 256 && t >= d) v = sc[t - d];
        __syncthreads();
        if (t < 256) sc[t] += v;
        __syncthreads();
    }

    if (t < NW) {
        const int offw = (t == 0) ? 0 : sc[t - 1];
        int b = offw;                  // base for this chunk, window t
        for (int gg = 0; gg < g; ++gg) b += lh[gg * NW + t];
        lbase[t] = b;
        if (g == 0) {
            offsets[t] = offw;
            counts_f[t] = (float)cnt_s[t];
            if (t == 0) offsets[NW] = sc[NW - 1];
        }
    }
    __syncthreads();

    if (i < N) {
        int cr = 0;                    // items of w in earlier waves
        #pragma unroll
        for (int wv2 = 0; wv2 < 16; ++wv2)
            if (wv2 < wv) cr += cw[wv2 * NW + w];
        const int lane = t & 63;
        const int wb = t & ~63;
        int r = 0;                     // stable rank within wave
        #pragma unroll
        for (int j = 0; j < 63; ++j)
            if (j < lane && lw[wb + j] == w) ++r;   // broadcast LDS reads
        const int p = lbase[w] + cr + r;            // global sorted position
        order_f[p] = (float)i;
        sorted_src[p] = i;
    }
}

// ---------------------------------------------------------------------------
// K3: output-ordered gather, engine-contiguous stores.
//  - each 32-lane engine owns 8 CONSECUTIVE slots -> its 8 NT stores form one
//    contiguous 4 KB run; each wave 8 KB; each block 32 KB in address order.
//  - pure-pad blocks (s0 >= cnt) take a uniform early branch: tight zero-fill
//    at fill rate, zero index loads (majority of blocks when MWS >> avg cnt).
//  - reads: regular (allocating) loads keep x MALL-resident across replays;
//    served by Infinity Cache in parallel with the HBM write stream.
// ---------------------------------------------------------------------------
__global__ __launch_bounds__(256) void k_gather(
                         const f32x4* __restrict__ x,
                         const int* __restrict__ sorted_src,
                         const int* __restrict__ offsets,
                         int N, int NW, int MWS, int bpw,
                         f32x4* __restrict__ out) {
    const int w  = blockIdx.x / bpw;                 // uniform
    const int s0 = (blockIdx.x - w * bpw) * RPB;     // uniform
    const int b  = blockIdx.y;
    const int t  = threadIdx.x;
    const int e  = t >> 5;                           // engine 0..7
    const int c4 = t & 31;                           // f32x4 lane in row

    const int off = offsets[w];                      // uniform (s_load)
    const int cnt = offsets[w + 1] - off;

    const long long ob = ((long long)b * NW + w) * MWS;
    const int se = s0 + e * 8;                       // engine's first slot

    if (s0 >= cnt) {
        // ---- pure pad block: straight sequential zero-fill ----
        const f32x4 z = {0.f, 0.f, 0.f, 0.f};
        #pragma unroll
        for (int k = 0; k < 8; ++k) {
            const int s = se + k;
            if (s < MWS)
                __builtin_nontemporal_store(z, &out[(ob + s) * 32 + c4]);
        }
        return;
    }

    const long long xb = (long long)b * N;

    // phase 1: 8 src-index loads (engine-uniform -> broadcast, L2-hot)
    int srcs[8];
    #pragma unroll
    for (int k = 0; k < 8; ++k) {
        const int s = se + k;
        srcs[k] = (s < cnt) ? sorted_src[off + s] : -1;
    }

    // phase 2: issue all 8 x-row loads (clamped addr -> unconditional)
    f32x4 v[8];
    #pragma unroll
    for (int k = 0; k < 8; ++k) {
        const int sc_ = (srcs[k] >= 0) ? srcs[k] : 0;
        v[k] = x[(xb + sc_) * 32 + c4];
    }

    // phase 3: zero-select pads, contiguous 4 KB NT store run per engine
    #pragma unroll
    for (int k = 0; k < 8; ++k) {
        const int s = se + k;
        if (s < MWS) {
            const f32x4 z = {0.f, 0.f, 0.f, 0.f};
            const f32x4 o = (srcs[k] >= 0) ? v[k] : z;
            __builtin_nontemporal_store(o, &out[(ob + s) * 32 + c4]);
        }
    }
}

// ---------------------------------------------------------------------------
extern "C" void kernel_launch(void* const* d_in, const int* in_sizes, int n_in,
                              void* d_out, int out_size, void* d_ws, size_t ws_size,
                              hipStream_t stream) {
    const float* x   = (const float*)d_in[0];
    const int*   wid = (const int*)d_in[1];

    const int N  = in_sizes[1];                 // 40962
    const int C  = 128;                         // per reference
    const int NW = 162;                         // per reference
    const int B  = (int)((long long)in_sizes[0] / ((long long)N * C));

    const long long win_elems = (long long)out_size - N - NW;
    const int MWS = (int)(win_elems / ((long long)B * NW * C));

    const int G = (N + CHUNK - 1) / CHUNK;      // 41 chunks

    // ws layout (ints): hist[G*NW] | offsets[NW+1] | sorted_src[N]
    int* hist       = (int*)d_ws;
    int* offsets    = hist + (size_t)G * NW;
    int* sorted_src = offsets + (NW + 1);

    float* out_f    = (float*)d_out;
    float* order_f  = out_f + win_elems;
    float* counts_f = order_f + N;

    const int bpw = (MWS + RPB - 1) / RPB;

    k_hist  <<<G, CHUNK, 0, stream>>>(wid, N, NW, hist);
    k_order <<<G, CHUNK, 0, stream>>>(wid, N, NW, G, hist, offsets,
                                      sorted_src, order_f, counts_f);
    k_gather<<<dim3(NW * bpw, B), 256, 0, stream>>>((const f32x4*)x, sorted_src,
                                                    offsets, N, NW, MWS, bpw,
                                                    (f32x4*)out_f);
}